// Round 6
// baseline (212.504 us; speedup 1.0000x reference)
//
#include <hip/hip_runtime.h>
#include <math.h>

#define NN   20000
#define EE   320000
#define ETOT 340000
#define FIN  128
#define HH   4
#define CC   64
#define HC   256
#define GG   64
#define BN_EPS 1e-5f
#define S1   384   // BcatT1 cols: 256 (W1, head-major) + 64 (Wskip) + 8 (es/ed) + 56 pad
#define S2   320   // BcatT2 cols: 256 (W2, head-major) + 8 (es/ed) + 56 pad
#define NBUCK 64   // BN-stats buckets (5000 blocks / 64 ~ 78 adds/address)
#define MAXDEG 64  // fixed-stride CSR row; P(Poisson(16)+1 >= 64) ~ 1e-22, fixed seed

typedef _Float16 v8h __attribute__((ext_vector_type(8)));
typedef _Float16 v4h __attribute__((ext_vector_type(4)));
typedef float    v4f __attribute__((ext_vector_type(4)));

__device__ __forceinline__ unsigned short f2bf(float f) {
    unsigned u = __float_as_uint(f);
    unsigned r = (u + 0x7FFF + ((u >> 16) & 1)) >> 16;   // RNE
    return (unsigned short)r;
}
__device__ __forceinline__ float bf2f(unsigned short u) {
    return __uint_as_float((unsigned)u << 16);
}
__device__ __forceinline__ float gelu_exact(float v) {
    return 0.5f * v * (1.f + erff(v * 0.70710678118654752f));
}

// ====== pre1: gbound | BcatT1 | BcatT2 | zero out/deg/sbuck (510 blocks) ==========
// W cols copied UNPERMUTED (head-major h4b layout): col c -> W[k][c].
__global__ __launch_bounds__(256) void pre1_kernel(
        const int* __restrict__ bidx, int* __restrict__ gstart,
        const float* __restrict__ W1, const float* __restrict__ Wskip,
        const float* __restrict__ W2,
        const float* __restrict__ as1, const float* __restrict__ ad1,
        const float* __restrict__ as2, const float* __restrict__ ad2,
        _Float16* __restrict__ BT1, _Float16* __restrict__ BT2,
        int* __restrict__ deg, float* __restrict__ sbuck1,
        float* __restrict__ sbuck2, float* __restrict__ outz) {
    int b = blockIdx.x, t = threadIdx.x;
    if (b < 79) {
        int i = b * 256 + t;
        if (i >= NN) return;
        int cur = bidx[i];
        if (i == 0) { for (int g = 0; g <= cur; ++g) gstart[g] = 0; }
        else { int prev = bidx[i - 1]; for (int g = prev + 1; g <= cur; ++g) gstart[g] = i; }
        if (i == NN - 1) { for (int g = cur + 1; g <= GG; ++g) gstart[g] = NN; }
    } else if (b < 271) {
        int i = (b - 79) * 256 + t;          // i < S1*FIN = 49152; BT1[col][k]
        int col = i >> 7, k = i & 127;
        float v;
        if (col < 256) {
            v = W1[k * 256 + col];           // head-major (no permutation)
        } else if (col < 320) {
            v = Wskip[k * 64 + (col - 256)];
        } else if (col < 328) {
            int kk = col - 320, h = kk & 3;
            const float* av = (kk < 4 ? as1 : ad1) + h * 64;
            const float* wr = W1 + k * 256 + h * 64;
            float s = 0.f;
            #pragma unroll 8
            for (int c = 0; c < 64; ++c) s += wr[c] * av[c];
            v = s;
        } else v = 0.f;
        BT1[i] = (_Float16)v;
    } else if (b < 351) {
        int i = (b - 271) * 256 + t;         // i < S2*CC = 20480; BT2[col][k]
        int col = i >> 6, k = i & 63;
        float v;
        if (col < 256) {
            v = W2[k * 256 + col];           // head-major (no permutation)
        } else if (col < 264) {
            int kk = col - 256, h = kk & 3;
            const float* av = (kk < 4 ? as2 : ad2) + h * 64;
            const float* wr = W2 + k * 256 + h * 64;
            float s = 0.f;
            #pragma unroll 8
            for (int c = 0; c < 64; ++c) s += wr[c] * av[c];
            v = s;
        } else v = 0.f;
        BT2[i] = (_Float16)v;
    } else if (b < 367) {
        int i = (b - 351) * 256 + t;         // GG*CC = 4096
        outz[i] = 0.f;
    } else if (b < 446) {
        int i = (b - 367) * 256 + t;
        if (i < NN) deg[i] = 0;
    } else if (b < 478) {
        int i = (b - 446) * 256 + t;         // NBUCK*128 = 8192
        sbuck1[i] = 0.f;
    } else {
        int i = (b - 478) * 256 + t;
        sbuck2[i] = 0.f;
    }
}

// ====== layer-1 GEMM: B in registers, A staged ONCE, zero k-loop barriers =========
// 625 blocks x 256 thr; block = one 32-row stripe x full 384 cols.
// wave w: col-frags w*6..w*6+5 (96 cols), BOTH row halves -> acc[2][6].
// B panel per wave: 6 frags x 4 ksteps x v8h = 96 VGPR, loaded once from BT1.
// (+ appended degree-count/CSR-fill blocks, co-scheduled as before)
__global__ __launch_bounds__(256) void gemm1_kernel(const float* __restrict__ A,
        const _Float16* __restrict__ BT,
        unsigned short* __restrict__ h4b, float* __restrict__ skipO,
        float* __restrict__ esf, float* __restrict__ edf,
        int ngemm, const int* __restrict__ ei, int* __restrict__ deg,
        int* __restrict__ csr) {
    int b = blockIdx.x;
    int t = threadIdx.x;
    if (b >= ngemm) {
        int i = (b - ngemm) * 256 + t;
        if (i >= ETOT) return;
        int s, d;
        if (i < EE) { s = ei[i]; d = ei[EE + i]; } else { s = i - EE; d = i - EE; }
        int p = atomicAdd(&deg[d], 1);
        if (p < MAXDEG) csr[d * MAXDEG + p] = s;   // overflow never triggers (1e-22)
        return;
    }
    __shared__ _Float16 sA[32][136];       // 272B rows: 2-way LDS aliasing only (free)
    int row0 = b * 32;                     // NN = 625*32 exact, no bounds needed
    {   // stage A once: 32 rows x 128 k; thread owns row t>>3, k (t&7)*16..+15
        int r = t >> 3, k0 = (t & 7) * 16;
        const float* src = &A[(size_t)(row0 + r) * FIN + k0];
        float4 f0 = *(const float4*)&src[0];
        float4 f1 = *(const float4*)&src[4];
        float4 f2 = *(const float4*)&src[8];
        float4 f3 = *(const float4*)&src[12];
        v8h h0, h1;
        h0[0] = (_Float16)f0.x; h0[1] = (_Float16)f0.y;
        h0[2] = (_Float16)f0.z; h0[3] = (_Float16)f0.w;
        h0[4] = (_Float16)f1.x; h0[5] = (_Float16)f1.y;
        h0[6] = (_Float16)f1.z; h0[7] = (_Float16)f1.w;
        h1[0] = (_Float16)f2.x; h1[1] = (_Float16)f2.y;
        h1[2] = (_Float16)f2.z; h1[3] = (_Float16)f2.w;
        h1[4] = (_Float16)f3.x; h1[5] = (_Float16)f3.y;
        h1[6] = (_Float16)f3.z; h1[7] = (_Float16)f3.w;
        *(v8h*)&sA[r][k0]     = h0;
        *(v8h*)&sA[r][k0 + 8] = h1;
    }
    int wave = t >> 6, lane = t & 63;
    int l15 = lane & 15, quad = lane >> 4;
    int cb0 = wave * 6;
    v8h bf[6][4];
    #pragma unroll
    for (int c = 0; c < 6; ++c)
        #pragma unroll
        for (int k = 0; k < 4; ++k)
            bf[c][k] = *(const v8h*)&BT[(size_t)((cb0 + c) * 16 + l15) * FIN + k * 32 + quad * 8];
    __syncthreads();
    v4f acc[2][6] = {};
    #pragma unroll
    for (int k = 0; k < 4; ++k) {
        v8h a0 = *(const v8h*)&sA[l15][k * 32 + quad * 8];
        v8h a1 = *(const v8h*)&sA[16 + l15][k * 32 + quad * 8];
        #pragma unroll
        for (int c = 0; c < 6; ++c) {
            acc[0][c] = __builtin_amdgcn_mfma_f32_16x16x32_f16(a0, bf[c][k], acc[0][c], 0, 0, 0);
            acc[1][c] = __builtin_amdgcn_mfma_f32_16x16x32_f16(a1, bf[c][k], acc[1][c], 0, 0, 0);
        }
    }
    // epilogue: D[row=quad*4+reg][col=l15] per 16x16 frag (verified mapping)
    #pragma unroll
    for (int rb = 0; rb < 2; ++rb) {
        #pragma unroll
        for (int c = 0; c < 6; ++c) {
            int gcol = (cb0 + c) * 16 + l15;
            #pragma unroll
            for (int reg = 0; reg < 4; ++reg) {
                int gr = row0 + rb * 16 + quad * 4 + reg;
                float v = acc[rb][c][reg];
                if (gcol < 256) {
                    h4b[(size_t)gr * HC + gcol] = f2bf(v);
                } else if (gcol < 320) {
                    skipO[(size_t)gr * CC + (gcol - 256)] = v;
                } else if (gcol < 328) {
                    if (gcol < 324) esf[gr * 4 + (gcol - 320)] = v;
                    else            edf[gr * 4 + (gcol - 324)] = v;
                }
            }
        }
    }
}

// ====== layer-2 GEMM: B in regs, fused BN1+skip+GELU A-stage done ONCE ===========
// 625 blocks; K=64 (2 ksteps), 320 cols -> wave w: frags w*5..w*5+4, acc[2][5].
__global__ __launch_bounds__(256) void gemm2_kernel(const float* __restrict__ gout,
        const float* __restrict__ skip, const float* __restrict__ sbuck,
        const float* __restrict__ g, const float* __restrict__ be,
        const float* __restrict__ bskip, float* __restrict__ hmid,
        const _Float16* __restrict__ BT,
        unsigned short* __restrict__ h4b,
        float* __restrict__ esf, float* __restrict__ edf) {
    __shared__ _Float16 sA[32][72];        // 144B rows: 2-way aliasing only
    __shared__ float tmp[128];
    __shared__ float sscale[64], sshift[64];
    int t = threadIdx.x;
    int b = blockIdx.x;
    if (t < 128) {
        float s = 0.f;
        #pragma unroll 16
        for (int k = 0; k < NBUCK; ++k) s += sbuck[k * 128 + t];
        tmp[t] = s;
    }
    __syncthreads();
    if (t < 64) {
        float mu  = tmp[t] * (1.f / NN);
        float var = tmp[64 + t] * (1.f / NN) - mu * mu;
        float inv = rsqrtf(var + BN_EPS) * g[t];
        sscale[t] = inv;
        sshift[t] = be[t] + bskip[t] - mu * inv;
    }
    __syncthreads();
    int row0 = b * 32;
    {   // stage A once with fused BN1+skip+GELU: thread owns row t>>3, ch (t&7)*8..+7
        int r = t >> 3, c0 = (t & 7) * 8;
        int gr = row0 + r;
        float4 q0 = *(const float4*)&gout[(size_t)gr * CC + c0];
        float4 q1 = *(const float4*)&gout[(size_t)gr * CC + c0 + 4];
        float4 p0 = *(const float4*)&skip[(size_t)gr * CC + c0];
        float4 p1 = *(const float4*)&skip[(size_t)gr * CC + c0 + 4];
        float qa[8] = {q0.x, q0.y, q0.z, q0.w, q1.x, q1.y, q1.z, q1.w};
        float pa[8] = {p0.x, p0.y, p0.z, p0.w, p1.x, p1.y, p1.z, p1.w};
        float vv[8];
        #pragma unroll
        for (int u = 0; u < 8; ++u)
            vv[u] = gelu_exact(qa[u] * sscale[c0 + u] + sshift[c0 + u] + pa[u]);
        *(float4*)&hmid[(size_t)gr * CC + c0]     = make_float4(vv[0], vv[1], vv[2], vv[3]);
        *(float4*)&hmid[(size_t)gr * CC + c0 + 4] = make_float4(vv[4], vv[5], vv[6], vv[7]);
        v8h hv;
        #pragma unroll
        for (int u = 0; u < 8; ++u) hv[u] = (_Float16)vv[u];
        *(v8h*)&sA[r][c0] = hv;
    }
    int wave = t >> 6, lane = t & 63;
    int l15 = lane & 15, quad = lane >> 4;
    int cb0 = wave * 5;
    v8h bf[5][2];
    #pragma unroll
    for (int c = 0; c < 5; ++c)
        #pragma unroll
        for (int k = 0; k < 2; ++k)
            bf[c][k] = *(const v8h*)&BT[(size_t)((cb0 + c) * 16 + l15) * CC + k * 32 + quad * 8];
    __syncthreads();
    v4f acc[2][5] = {};
    #pragma unroll
    for (int k = 0; k < 2; ++k) {
        v8h a0 = *(const v8h*)&sA[l15][k * 32 + quad * 8];
        v8h a1 = *(const v8h*)&sA[16 + l15][k * 32 + quad * 8];
        #pragma unroll
        for (int c = 0; c < 5; ++c) {
            acc[0][c] = __builtin_amdgcn_mfma_f32_16x16x32_f16(a0, bf[c][k], acc[0][c], 0, 0, 0);
            acc[1][c] = __builtin_amdgcn_mfma_f32_16x16x32_f16(a1, bf[c][k], acc[1][c], 0, 0, 0);
        }
    }
    #pragma unroll
    for (int rb = 0; rb < 2; ++rb) {
        #pragma unroll
        for (int c = 0; c < 5; ++c) {
            int gcol = (cb0 + c) * 16 + l15;
            #pragma unroll
            for (int reg = 0; reg < 4; ++reg) {
                int gr = row0 + rb * 16 + quad * 4 + reg;
                float v = acc[rb][c][reg];
                if (gcol < 256) {
                    h4b[(size_t)gr * HC + gcol] = f2bf(v);
                } else if (gcol < 264) {
                    if (gcol < 260) esf[gr * 4 + (gcol - 256)] = v;
                    else            edf[gr * 4 + (gcol - 260)] = v;
                }
            }
        }
    }
}

// ====== aggregation + fused BN statistics (R3 measured-best, untouched) ===========
// grid = NN/4 = 5000 blocks; lane owns head=lane>>4, channels (lane&15)*4..+3.
__global__ __launch_bounds__(256) void aggr_kernel(const unsigned short* __restrict__ h4b,
        const float* __restrict__ esf, const float* __restrict__ edf,
        const int* __restrict__ deg, const int* __restrict__ csr_src,
        const float* __restrict__ bias, float* __restrict__ out,
        float* __restrict__ sbuck) {
    int wave = threadIdx.x >> 6, lane = threadIdx.x & 63;
    int head = lane >> 4;
    int n = blockIdx.x * 4 + wave;
    float edn = edf[n * 4 + head];
    float4 acc = make_float4(0.f, 0.f, 0.f, 0.f);
    float ssum = 0.f;
    int dn = deg[n];
    dn = (dn < MAXDEG) ? dn : MAXDEG;      // memory safety; never triggers
    int beg = n * MAXDEG, end = beg + dn;
    int j = beg;
    for (; j + 4 <= end; j += 4) {
        int4 s4 = *(const int4*)&csr_src[j];
        float E0 = esf[s4.x * 4 + head];
        float E1 = esf[s4.y * 4 + head];
        float E2 = esf[s4.z * 4 + head];
        float E3 = esf[s4.w * 4 + head];
        ushort4 v0 = *(const ushort4*)&h4b[(size_t)s4.x * HC + lane * 4];
        ushort4 v1 = *(const ushort4*)&h4b[(size_t)s4.y * HC + lane * 4];
        ushort4 v2 = *(const ushort4*)&h4b[(size_t)s4.z * HC + lane * 4];
        ushort4 v3 = *(const ushort4*)&h4b[(size_t)s4.w * HC + lane * 4];
        float e0 = E0 + edn; e0 = fmaxf(e0, 0.2f * e0); float w0 = __expf(e0);
        float e1 = E1 + edn; e1 = fmaxf(e1, 0.2f * e1); float w1 = __expf(e1);
        float e2 = E2 + edn; e2 = fmaxf(e2, 0.2f * e2); float w2 = __expf(e2);
        float e3 = E3 + edn; e3 = fmaxf(e3, 0.2f * e3); float w3 = __expf(e3);
        acc.x += w0 * bf2f(v0.x); acc.y += w0 * bf2f(v0.y);
        acc.z += w0 * bf2f(v0.z); acc.w += w0 * bf2f(v0.w); ssum += w0;
        acc.x += w1 * bf2f(v1.x); acc.y += w1 * bf2f(v1.y);
        acc.z += w1 * bf2f(v1.z); acc.w += w1 * bf2f(v1.w); ssum += w1;
        acc.x += w2 * bf2f(v2.x); acc.y += w2 * bf2f(v2.y);
        acc.z += w2 * bf2f(v2.z); acc.w += w2 * bf2f(v2.w); ssum += w2;
        acc.x += w3 * bf2f(v3.x); acc.y += w3 * bf2f(v3.y);
        acc.z += w3 * bf2f(v3.z); acc.w += w3 * bf2f(v3.w); ssum += w3;
    }
    for (; j < end; ++j) {
        int s = csr_src[j];
        float E = esf[s * 4 + head];
        ushort4 v = *(const ushort4*)&h4b[(size_t)s * HC + lane * 4];
        float e = E + edn; e = fmaxf(e, 0.2f * e); float w = __expf(e);
        acc.x += w * bf2f(v.x); acc.y += w * bf2f(v.y);
        acc.z += w * bf2f(v.z); acc.w += w * bf2f(v.w); ssum += w;
    }
    float inv = 1.f / (ssum + 1e-16f);
    float4 r;
    r.x = acc.x * inv; r.y = acc.y * inv; r.z = acc.z * inv; r.w = acc.w * inv;
    // head-sum: lanes {l, l^16, l^32, l^48} hold the 4 heads of the same channels
    r.x += __shfl_xor(r.x, 16); r.y += __shfl_xor(r.y, 16);
    r.z += __shfl_xor(r.z, 16); r.w += __shfl_xor(r.w, 16);
    r.x += __shfl_xor(r.x, 32); r.y += __shfl_xor(r.y, 32);
    r.z += __shfl_xor(r.z, 32); r.w += __shfl_xor(r.w, 32);
    __shared__ float ls[4][64], lq[4][64];
    if (lane < 16) {
        float4 b4 = *(const float4*)&bias[lane * 4];
        float4 o;
        o.x = 0.25f * r.x + b4.x; o.y = 0.25f * r.y + b4.y;
        o.z = 0.25f * r.z + b4.z; o.w = 0.25f * r.w + b4.w;
        *(float4*)&out[n * CC + lane * 4] = o;
        *(float4*)&ls[wave][lane * 4] = o;
        float4 q;
        q.x = o.x * o.x; q.y = o.y * o.y; q.z = o.z * o.z; q.w = o.w * o.w;
        *(float4*)&lq[wave][lane * 4] = q;
    }
    __syncthreads();
    if (wave == 0) {
        float s = ls[0][lane] + ls[1][lane] + ls[2][lane] + ls[3][lane];
        float q = lq[0][lane] + lq[1][lane] + lq[2][lane] + lq[3][lane];
        int bk = (blockIdx.x & (NBUCK - 1)) * 128;
        atomicAdd(&sbuck[bk + lane], s);
        atomicAdd(&sbuck[bk + 64 + lane], q);
    }
}

// ---------------- BN apply, layer 2 + fused mean-pool (4-node combined atomics) ----
__global__ __launch_bounds__(256) void bnapply2_kernel(const float* __restrict__ gout,
        const float* __restrict__ sbuck, const float* __restrict__ g,
        const float* __restrict__ be, const float* __restrict__ resid,
        const int* __restrict__ bidx, const int* __restrict__ gstart,
        float* __restrict__ out) {
    __shared__ float tmp[128];
    __shared__ float smu[64], sinv[64];
    __shared__ float ls[4][64];
    __shared__ int gi[4];
    int t = threadIdx.x;
    if (t < 128) {
        float s = 0.f;
        #pragma unroll 16
        for (int k = 0; k < NBUCK; ++k) s += sbuck[k * 128 + t];
        tmp[t] = s;
    }
    __syncthreads();
    if (t < 64) {
        float mu  = tmp[t] * (1.f / NN);
        float var = tmp[64 + t] * (1.f / NN) - mu * mu;
        smu[t] = mu;
        sinv[t] = rsqrtf(var + BN_EPS) * g[t];
    }
    __syncthreads();
    int i = blockIdx.x * 256 + t;
    int ch = i & 63;
    int wave = t >> 6;
    int n = i >> 6;
    float v = (gout[i] - smu[ch]) * sinv[ch] + be[ch] + resid[i];
    v = gelu_exact(v);
    int gg = bidx[n];
    int cnt = gstart[gg + 1] - gstart[gg];
    ls[wave][ch] = v * (1.f / (float)cnt);
    if (ch == 0) gi[wave] = gg;
    __syncthreads();
    if (wave == 0) {
        if (gi[0] == gi[1] && gi[1] == gi[2] && gi[2] == gi[3]) {
            float s = ls[0][ch] + ls[1][ch] + ls[2][ch] + ls[3][ch];
            atomicAdd(&out[gi[0] * CC + ch], s);
        } else {
            #pragma unroll
            for (int w2 = 0; w2 < 4; ++w2)
                atomicAdd(&out[gi[w2] * CC + ch], ls[w2][ch]);
        }
    }
}

extern "C" void kernel_launch(void* const* d_in, const int* in_sizes, int n_in,
                              void* d_out, int out_size, void* d_ws, size_t ws_size,
                              hipStream_t stream) {
    const float* x      = (const float*)d_in[0];
    const float* W1     = (const float*)d_in[1];
    const float* a_src1 = (const float*)d_in[2];
    const float* a_dst1 = (const float*)d_in[3];
    const float* b1     = (const float*)d_in[4];
    const float* Wskip  = (const float*)d_in[5];
    const float* bskip  = (const float*)d_in[6];
    const float* g1     = (const float*)d_in[7];
    const float* be1    = (const float*)d_in[8];
    const float* W2     = (const float*)d_in[9];
    const float* a_src2 = (const float*)d_in[10];
    const float* a_dst2 = (const float*)d_in[11];
    const float* b2     = (const float*)d_in[12];
    const float* g2     = (const float*)d_in[13];
    const float* be2    = (const float*)d_in[14];
    const int*   ei     = (const int*)d_in[15];
    const int*   bidx   = (const int*)d_in[16];
    float* out = (float*)d_out;

    char* w = (char*)d_ws;
    size_t o = 0;
    auto alloc = [&](size_t bytes) -> void* {
        void* p = w + o;
        o = (o + bytes + 255) & ~(size_t)255;
        return p;
    };

    unsigned short* h4b = (unsigned short*)alloc((size_t)NN * HC * 2);  // bf16 [N][H][C]
    float* esf = (float*)alloc((size_t)NN * 16);
    float* edf = (float*)alloc((size_t)NN * 16);
    float* skip = (float*)alloc((size_t)NN * CC * 4);
    float* gout = (float*)alloc((size_t)NN * CC * 4);
    float* hmid = (float*)alloc((size_t)NN * CC * 4);
    _Float16* BT1 = (_Float16*)alloc((size_t)S1 * FIN * 2);
    _Float16* BT2 = (_Float16*)alloc((size_t)S2 * CC * 2);
    int* csr    = (int*)alloc((size_t)NN * MAXDEG * 4);
    int* gstart = (int*)alloc((size_t)(GG + 1) * 4);
    int* deg      = (int*)alloc((size_t)NN * 4);
    float* sbuck1 = (float*)alloc((size_t)NBUCK * 128 * 4);
    float* sbuck2 = (float*)alloc((size_t)NBUCK * 128 * 4);

    int ebk = (ETOT + 255) / 256;   // 1329
    int ngemm = NN / 32;            // 625 (exact)
    int nodeblk = NN / 4;           // 5000 (NN % 4 == 0)

    // ---- pre: gbound | BcatT1 | BcatT2 | zero out/deg/sbuck (no memset dispatch) --
    pre1_kernel<<<510, 256, 0, stream>>>(bidx, gstart,
            W1, Wskip, W2, a_src1, a_dst1, a_src2, a_dst2, BT1, BT2,
            deg, sbuck1, sbuck2, out);

    // ---- layer 1 GEMM (625 blocks, B-in-regs) + degree-count+CSR-fill (1329) -----
    gemm1_kernel<<<ngemm + ebk, 256, 0, stream>>>(x, BT1,
            h4b, skip, esf, edf, ngemm, ei, deg, csr);
    // ---- layer 1 aggregation (+bucketed BN stats) ----
    aggr_kernel<<<nodeblk, 256, 0, stream>>>(h4b, esf, edf, deg, csr, b1, gout,
            sbuck1);

    // ---- layer 2 GEMM with fused BN1+skip+GELU A-staging (writes hmid too) ----
    gemm2_kernel<<<ngemm, 256, 0, stream>>>(gout, skip, sbuck1, g1, be1, bskip,
            hmid, BT2, h4b, esf, edf);
    aggr_kernel<<<nodeblk, 256, 0, stream>>>(h4b, esf, edf, deg, csr, b2, gout,
            sbuck2);
    bnapply2_kernel<<<NN * CC / 256, 256, 0, stream>>>(
        gout, sbuck2, g2, be2, hmid, bidx, gstart, out);
}

// Round 7
// 201.329 us; speedup vs baseline: 1.0555x; 1.0555x over previous
//
#include <hip/hip_runtime.h>
#include <math.h>

#define NN   20000
#define EE   320000
#define ETOT 340000
#define FIN  128
#define HH   4
#define CC   64
#define HC   256
#define GG   64
#define BN_EPS 1e-5f
#define S1   384   // BcatT1 cols: 256 (W1, head-major) + 64 (Wskip) + 8 (es/ed) + 56 pad
#define S2   320   // BcatT2 cols: 256 (W2, head-major) + 8 (es/ed) + 56 pad
#define NBUCK 64   // BN-stats buckets (5000 blocks / 64 ~ 78 adds/address)
#define MAXDEG 64  // fixed-stride CSR row; P(Poisson(16)+1 >= 64) ~ 1e-22, fixed seed

typedef _Float16 v8h __attribute__((ext_vector_type(8)));
typedef _Float16 v4h __attribute__((ext_vector_type(4)));
typedef float    v4f __attribute__((ext_vector_type(4)));

__device__ __forceinline__ float gelu_exact(float v) {
    return 0.5f * v * (1.f + erff(v * 0.70710678118654752f));
}

// ====== pre1: gbound | BcatT1 | BcatT2 | zero out/deg/sbuck (510 blocks) ==========
// W cols copied UNPERMUTED (head-major h4b layout): col c -> W[k][c].
__global__ __launch_bounds__(256) void pre1_kernel(
        const int* __restrict__ bidx, int* __restrict__ gstart,
        const float* __restrict__ W1, const float* __restrict__ Wskip,
        const float* __restrict__ W2,
        const float* __restrict__ as1, const float* __restrict__ ad1,
        const float* __restrict__ as2, const float* __restrict__ ad2,
        _Float16* __restrict__ BT1, _Float16* __restrict__ BT2,
        int* __restrict__ deg, float* __restrict__ sbuck1,
        float* __restrict__ sbuck2, float* __restrict__ outz) {
    int b = blockIdx.x, t = threadIdx.x;
    if (b < 79) {
        int i = b * 256 + t;
        if (i >= NN) return;
        int cur = bidx[i];
        if (i == 0) { for (int g = 0; g <= cur; ++g) gstart[g] = 0; }
        else { int prev = bidx[i - 1]; for (int g = prev + 1; g <= cur; ++g) gstart[g] = i; }
        if (i == NN - 1) { for (int g = cur + 1; g <= GG; ++g) gstart[g] = NN; }
    } else if (b < 271) {
        int i = (b - 79) * 256 + t;          // i < S1*FIN = 49152; BT1[col][k]
        int col = i >> 7, k = i & 127;
        float v;
        if (col < 256) {
            v = W1[k * 256 + col];           // head-major (no permutation)
        } else if (col < 320) {
            v = Wskip[k * 64 + (col - 256)];
        } else if (col < 328) {
            int kk = col - 320, h = kk & 3;
            const float* av = (kk < 4 ? as1 : ad1) + h * 64;
            const float* wr = W1 + k * 256 + h * 64;
            float s = 0.f;
            #pragma unroll 8
            for (int c = 0; c < 64; ++c) s += wr[c] * av[c];
            v = s;
        } else v = 0.f;
        BT1[i] = (_Float16)v;
    } else if (b < 351) {
        int i = (b - 271) * 256 + t;         // i < S2*CC = 20480; BT2[col][k]
        int col = i >> 6, k = i & 63;
        float v;
        if (col < 256) {
            v = W2[k * 256 + col];           // head-major (no permutation)
        } else if (col < 264) {
            int kk = col - 256, h = kk & 3;
            const float* av = (kk < 4 ? as2 : ad2) + h * 64;
            const float* wr = W2 + k * 256 + h * 64;
            float s = 0.f;
            #pragma unroll 8
            for (int c = 0; c < 64; ++c) s += wr[c] * av[c];
            v = s;
        } else v = 0.f;
        BT2[i] = (_Float16)v;
    } else if (b < 367) {
        int i = (b - 351) * 256 + t;         // GG*CC = 4096
        outz[i] = 0.f;
    } else if (b < 446) {
        int i = (b - 367) * 256 + t;
        if (i < NN) deg[i] = 0;
    } else if (b < 478) {
        int i = (b - 446) * 256 + t;         // NBUCK*128 = 8192
        sbuck1[i] = 0.f;
    } else {
        int i = (b - 478) * 256 + t;
        sbuck2[i] = 0.f;
    }
}

// ====== fused MFMA fp16 GEMM, 32-row x half-width tiles (R3 measured-best) ========
// h4b now stored as fp16 (1-op cvt in epilogue; enables v_fma_mix in aggr).
template<int NCB>
__global__ __launch_bounds__(256) void gemm_mfma(const float* __restrict__ A,
        const _Float16* __restrict__ BT, int M, int K,
        _Float16* __restrict__ h4b, float* __restrict__ skipO,
        float* __restrict__ esf, float* __restrict__ edf,
        int escol0, int ngemm, int do_fill,
        const int* __restrict__ ei, int* __restrict__ deg,
        int* __restrict__ csr) {
    int b = blockIdx.x;
    int t = threadIdx.x;
    if (do_fill && b >= ngemm) {
        int i = (b - ngemm) * 256 + t;
        if (i >= ETOT) return;
        int s, d;
        if (i < EE) { s = ei[i]; d = ei[EE + i]; } else { s = i - EE; d = i - EE; }
        int p = atomicAdd(&deg[d], 1);
        if (p < MAXDEG) csr[d * MAXDEG + p] = s;   // overflow never triggers (1e-22)
        return;
    }
    const int COLT = 2 * NCB * 16;         // 192
    __shared__ _Float16 sA[32][40];        // [row][k], 80B rows
    __shared__ _Float16 sBT[2 * NCB * 16][40];
    int tile = b & 1;
    int col0 = tile * COLT;
    int row0 = (b >> 1) * 32;
    int wave = t >> 6, lane = t & 63;
    int l15 = lane & 15, quad = lane >> 4;
    int rb  = wave & 1;                    // row-frag 0/1
    int cb0 = (wave >> 1) * NCB;           // col-frag base
    v4f acc[NCB] = {};
    for (int k0 = 0; k0 < K; k0 += 32) {
        {   // stage A: 32 rows x 32 k, fp32 -> fp16 (one float4 per thread)
            int r = t >> 3, c4 = t & 7;
            int gr = row0 + r;
            float4 v0 = make_float4(0.f, 0.f, 0.f, 0.f);
            if (gr < M) v0 = *(const float4*)&A[(size_t)gr * K + k0 + c4 * 4];
            v4h hv;
            hv[0] = (_Float16)v0.x; hv[1] = (_Float16)v0.y;
            hv[2] = (_Float16)v0.z; hv[3] = (_Float16)v0.w;
            *(v4h*)&sA[r][c4 * 4] = hv;
        }
        for (int j = t; j < COLT * 4; j += 256) {
            int c = j >> 2, s = j & 3;
            *(v8h*)&sBT[c][s * 8] = *(const v8h*)&BT[(size_t)(col0 + c) * K + k0 + s * 8];
        }
        __syncthreads();
        v8h af = *(const v8h*)&sA[rb * 16 + l15][quad * 8];
        #pragma unroll
        for (int c = 0; c < NCB; ++c) {
            v8h bf = *(const v8h*)&sBT[(cb0 + c) * 16 + l15][quad * 8];
            acc[c] = __builtin_amdgcn_mfma_f32_16x16x32_f16(af, bf, acc[c], 0, 0, 0);
        }
        __syncthreads();
    }
    // epilogue: D[row=quad*4+reg][col=l15] per 16x16 frag (verified mapping)
    #pragma unroll
    for (int c = 0; c < NCB; ++c) {
        int gcol = col0 + (cb0 + c) * 16 + l15;
        #pragma unroll
        for (int reg = 0; reg < 4; ++reg) {
            int gr = row0 + rb * 16 + quad * 4 + reg;
            if (gr >= M) continue;
            float v = acc[c][reg];
            if (gcol < 256) {
                h4b[(size_t)gr * HC + gcol] = (_Float16)v;
            } else if (skipO != nullptr && gcol < 320) {
                skipO[(size_t)gr * CC + (gcol - 256)] = v;
            } else if (gcol >= escol0 && gcol < escol0 + 8) {
                if (gcol < escol0 + 4) esf[gr * 4 + (gcol - escol0)] = v;
                else                   edf[gr * 4 + (gcol - escol0 - 4)] = v;
            }
        }
    }
}

// ====== layer-2 GEMM with fused BN1+skip+GELU A-staging (R3 structure) ============
template<int NCB>
__global__ __launch_bounds__(256) void gemm_mfma_bn(const float* __restrict__ gout,
        const float* __restrict__ skip, const float* __restrict__ sbuck,
        const float* __restrict__ g, const float* __restrict__ be,
        const float* __restrict__ bskip, float* __restrict__ hmid,
        const _Float16* __restrict__ BT, int M, int K,
        _Float16* __restrict__ h4b,
        float* __restrict__ esf, float* __restrict__ edf, int escol0) {
    const int COLT = 2 * NCB * 16;         // 160
    __shared__ _Float16 sA[32][40];
    __shared__ _Float16 sBT[2 * NCB * 16][40];
    __shared__ float tmp[128];
    __shared__ float sscale[64], sshift[64];
    int t = threadIdx.x;
    int b = blockIdx.x;
    if (t < 128) {
        float s = 0.f;
        #pragma unroll 16
        for (int k = 0; k < NBUCK; ++k) s += sbuck[k * 128 + t];
        tmp[t] = s;
    }
    __syncthreads();
    if (t < 64) {
        float mu  = tmp[t] * (1.f / NN);
        float var = tmp[64 + t] * (1.f / NN) - mu * mu;
        float inv = rsqrtf(var + BN_EPS) * g[t];
        sscale[t] = inv;
        sshift[t] = be[t] + bskip[t] - mu * inv;
    }
    __syncthreads();
    int tile = b & 1;
    int col0 = tile * COLT;
    int row0 = (b >> 1) * 32;
    int wave = t >> 6, lane = t & 63;
    int l15 = lane & 15, quad = lane >> 4;
    int rb  = wave & 1;
    int cb0 = (wave >> 1) * NCB;
    v4f acc[NCB] = {};
    for (int k0 = 0; k0 < K; k0 += 32) {
        {   // stage A with fused BN1+skip+GELU: 32 rows x 32 ch, float4/thread
            int r = t >> 3, c4 = t & 7;
            int gr = row0 + r;
            int cb = k0 + c4 * 4;          // channel base
            float vv[4];
            if (gr < M) {
                float4 q = *(const float4*)&gout[(size_t)gr * CC + cb];
                float4 p = *(const float4*)&skip[(size_t)gr * CC + cb];
                float qa[4] = {q.x, q.y, q.z, q.w};
                float pa[4] = {p.x, p.y, p.z, p.w};
                #pragma unroll
                for (int u = 0; u < 4; ++u)
                    vv[u] = gelu_exact(qa[u] * sscale[cb + u] + sshift[cb + u] + pa[u]);
                if (tile == 0)
                    *(float4*)&hmid[(size_t)gr * CC + cb] =
                        make_float4(vv[0], vv[1], vv[2], vv[3]);
            } else {
                vv[0] = vv[1] = vv[2] = vv[3] = 0.f;
            }
            v4h hv;
            hv[0] = (_Float16)vv[0]; hv[1] = (_Float16)vv[1];
            hv[2] = (_Float16)vv[2]; hv[3] = (_Float16)vv[3];
            *(v4h*)&sA[r][c4 * 4] = hv;
        }
        for (int j = t; j < COLT * 4; j += 256) {
            int c = j >> 2, s = j & 3;
            *(v8h*)&sBT[c][s * 8] = *(const v8h*)&BT[(size_t)(col0 + c) * K + k0 + s * 8];
        }
        __syncthreads();
        v8h af = *(const v8h*)&sA[rb * 16 + l15][quad * 8];
        #pragma unroll
        for (int c = 0; c < NCB; ++c) {
            v8h bf = *(const v8h*)&sBT[(cb0 + c) * 16 + l15][quad * 8];
            acc[c] = __builtin_amdgcn_mfma_f32_16x16x32_f16(af, bf, acc[c], 0, 0, 0);
        }
        __syncthreads();
    }
    #pragma unroll
    for (int c = 0; c < NCB; ++c) {
        int gcol = col0 + (cb0 + c) * 16 + l15;
        #pragma unroll
        for (int reg = 0; reg < 4; ++reg) {
            int gr = row0 + rb * 16 + quad * 4 + reg;
            if (gr >= M) continue;
            float v = acc[c][reg];
            if (gcol < 256) {
                h4b[(size_t)gr * HC + gcol] = (_Float16)v;
            } else if (gcol >= escol0 && gcol < escol0 + 8) {
                if (gcol < escol0 + 4) esf[gr * 4 + (gcol - escol0)] = v;
                else                   edf[gr * 4 + (gcol - escol0 - 4)] = v;
            }
        }
    }
}

// ====== aggregation + fused BN statistics (head-major, fp16 h4b + fma_mix) ========
// grid = NN/4 = 5000 blocks; lane owns head=lane>>4, channels (lane&15)*4..+3.
// fp16 h rows: (float)h16 * w + acc pattern -> v_fma_mix_f32, no unpack VALU.
__global__ __launch_bounds__(256) void aggr_kernel(const _Float16* __restrict__ h4b,
        const float* __restrict__ esf, const float* __restrict__ edf,
        const int* __restrict__ deg, const int* __restrict__ csr_src,
        const float* __restrict__ bias, float* __restrict__ out,
        float* __restrict__ sbuck) {
    int wave = threadIdx.x >> 6, lane = threadIdx.x & 63;
    int head = lane >> 4;
    int n = blockIdx.x * 4 + wave;
    float edn = edf[n * 4 + head];
    float4 acc = make_float4(0.f, 0.f, 0.f, 0.f);
    float ssum = 0.f;
    int dn = deg[n];
    dn = (dn < MAXDEG) ? dn : MAXDEG;      // memory safety; never triggers
    int beg = n * MAXDEG, end = beg + dn;
    int j = beg;
    for (; j + 4 <= end; j += 4) {
        int4 s4 = *(const int4*)&csr_src[j];
        float E0 = esf[s4.x * 4 + head];
        float E1 = esf[s4.y * 4 + head];
        float E2 = esf[s4.z * 4 + head];
        float E3 = esf[s4.w * 4 + head];
        v4h v0 = *(const v4h*)&h4b[(size_t)s4.x * HC + lane * 4];
        v4h v1 = *(const v4h*)&h4b[(size_t)s4.y * HC + lane * 4];
        v4h v2 = *(const v4h*)&h4b[(size_t)s4.z * HC + lane * 4];
        v4h v3 = *(const v4h*)&h4b[(size_t)s4.w * HC + lane * 4];
        float e0 = E0 + edn; e0 = fmaxf(e0, 0.2f * e0); float w0 = __expf(e0);
        float e1 = E1 + edn; e1 = fmaxf(e1, 0.2f * e1); float w1 = __expf(e1);
        float e2 = E2 + edn; e2 = fmaxf(e2, 0.2f * e2); float w2 = __expf(e2);
        float e3 = E3 + edn; e3 = fmaxf(e3, 0.2f * e3); float w3 = __expf(e3);
        acc.x += w0 * (float)v0[0]; acc.y += w0 * (float)v0[1];
        acc.z += w0 * (float)v0[2]; acc.w += w0 * (float)v0[3]; ssum += w0;
        acc.x += w1 * (float)v1[0]; acc.y += w1 * (float)v1[1];
        acc.z += w1 * (float)v1[2]; acc.w += w1 * (float)v1[3]; ssum += w1;
        acc.x += w2 * (float)v2[0]; acc.y += w2 * (float)v2[1];
        acc.z += w2 * (float)v2[2]; acc.w += w2 * (float)v2[3]; ssum += w2;
        acc.x += w3 * (float)v3[0]; acc.y += w3 * (float)v3[1];
        acc.z += w3 * (float)v3[2]; acc.w += w3 * (float)v3[3]; ssum += w3;
    }
    for (; j < end; ++j) {
        int s = csr_src[j];
        float E = esf[s * 4 + head];
        v4h v = *(const v4h*)&h4b[(size_t)s * HC + lane * 4];
        float e = E + edn; e = fmaxf(e, 0.2f * e); float w = __expf(e);
        acc.x += w * (float)v[0]; acc.y += w * (float)v[1];
        acc.z += w * (float)v[2]; acc.w += w * (float)v[3]; ssum += w;
    }
    float inv = 1.f / (ssum + 1e-16f);
    float4 r;
    r.x = acc.x * inv; r.y = acc.y * inv; r.z = acc.z * inv; r.w = acc.w * inv;
    // head-sum: lanes {l, l^16, l^32, l^48} hold the 4 heads of the same channels
    r.x += __shfl_xor(r.x, 16); r.y += __shfl_xor(r.y, 16);
    r.z += __shfl_xor(r.z, 16); r.w += __shfl_xor(r.w, 16);
    r.x += __shfl_xor(r.x, 32); r.y += __shfl_xor(r.y, 32);
    r.z += __shfl_xor(r.z, 32); r.w += __shfl_xor(r.w, 32);
    __shared__ float ls[4][64], lq[4][64];
    if (lane < 16) {
        float4 b4 = *(const float4*)&bias[lane * 4];
        float4 o;
        o.x = 0.25f * r.x + b4.x; o.y = 0.25f * r.y + b4.y;
        o.z = 0.25f * r.z + b4.z; o.w = 0.25f * r.w + b4.w;
        *(float4*)&out[n * CC + lane * 4] = o;
        *(float4*)&ls[wave][lane * 4] = o;
        float4 q;
        q.x = o.x * o.x; q.y = o.y * o.y; q.z = o.z * o.z; q.w = o.w * o.w;
        *(float4*)&lq[wave][lane * 4] = q;
    }
    __syncthreads();
    if (wave == 0) {
        float s = ls[0][lane] + ls[1][lane] + ls[2][lane] + ls[3][lane];
        float q = lq[0][lane] + lq[1][lane] + lq[2][lane] + lq[3][lane];
        int bk = (blockIdx.x & (NBUCK - 1)) * 128;
        atomicAdd(&sbuck[bk + lane], s);
        atomicAdd(&sbuck[bk + 64 + lane], q);
    }
}

// ---------------- BN apply, layer 2 + fused mean-pool (4-node combined atomics) ----
__global__ __launch_bounds__(256) void bnapply2_kernel(const float* __restrict__ gout,
        const float* __restrict__ sbuck, const float* __restrict__ g,
        const float* __restrict__ be, const float* __restrict__ resid,
        const int* __restrict__ bidx, const int* __restrict__ gstart,
        float* __restrict__ out) {
    __shared__ float tmp[128];
    __shared__ float smu[64], sinv[64];
    __shared__ float ls[4][64];
    __shared__ int gi[4];
    int t = threadIdx.x;
    if (t < 128) {
        float s = 0.f;
        #pragma unroll 16
        for (int k = 0; k < NBUCK; ++k) s += sbuck[k * 128 + t];
        tmp[t] = s;
    }
    __syncthreads();
    if (t < 64) {
        float mu  = tmp[t] * (1.f / NN);
        float var = tmp[64 + t] * (1.f / NN) - mu * mu;
        smu[t] = mu;
        sinv[t] = rsqrtf(var + BN_EPS) * g[t];
    }
    __syncthreads();
    int i = blockIdx.x * 256 + t;
    int ch = i & 63;
    int wave = t >> 6;
    int n = i >> 6;
    float v = (gout[i] - smu[ch]) * sinv[ch] + be[ch] + resid[i];
    v = gelu_exact(v);
    int gg = bidx[n];
    int cnt = gstart[gg + 1] - gstart[gg];
    ls[wave][ch] = v * (1.f / (float)cnt);
    if (ch == 0) gi[wave] = gg;
    __syncthreads();
    if (wave == 0) {
        if (gi[0] == gi[1] && gi[1] == gi[2] && gi[2] == gi[3]) {
            float s = ls[0][ch] + ls[1][ch] + ls[2][ch] + ls[3][ch];
            atomicAdd(&out[gi[0] * CC + ch], s);
        } else {
            #pragma unroll
            for (int w2 = 0; w2 < 4; ++w2)
                atomicAdd(&out[gi[w2] * CC + ch], ls[w2][ch]);
        }
    }
}

extern "C" void kernel_launch(void* const* d_in, const int* in_sizes, int n_in,
                              void* d_out, int out_size, void* d_ws, size_t ws_size,
                              hipStream_t stream) {
    const float* x      = (const float*)d_in[0];
    const float* W1     = (const float*)d_in[1];
    const float* a_src1 = (const float*)d_in[2];
    const float* a_dst1 = (const float*)d_in[3];
    const float* b1     = (const float*)d_in[4];
    const float* Wskip  = (const float*)d_in[5];
    const float* bskip  = (const float*)d_in[6];
    const float* g1     = (const float*)d_in[7];
    const float* be1    = (const float*)d_in[8];
    const float* W2     = (const float*)d_in[9];
    const float* a_src2 = (const float*)d_in[10];
    const float* a_dst2 = (const float*)d_in[11];
    const float* b2     = (const float*)d_in[12];
    const float* g2     = (const float*)d_in[13];
    const float* be2    = (const float*)d_in[14];
    const int*   ei     = (const int*)d_in[15];
    const int*   bidx   = (const int*)d_in[16];
    float* out = (float*)d_out;

    char* w = (char*)d_ws;
    size_t o = 0;
    auto alloc = [&](size_t bytes) -> void* {
        void* p = w + o;
        o = (o + bytes + 255) & ~(size_t)255;
        return p;
    };

    _Float16* h4b = (_Float16*)alloc((size_t)NN * HC * 2);   // fp16 [N][H][C]
    float* esf = (float*)alloc((size_t)NN * 16);
    float* edf = (float*)alloc((size_t)NN * 16);
    float* skip = (float*)alloc((size_t)NN * CC * 4);
    float* gout = (float*)alloc((size_t)NN * CC * 4);
    float* hmid = (float*)alloc((size_t)NN * CC * 4);
    _Float16* BT1 = (_Float16*)alloc((size_t)S1 * FIN * 2);
    _Float16* BT2 = (_Float16*)alloc((size_t)S2 * CC * 2);
    int* csr    = (int*)alloc((size_t)NN * MAXDEG * 4);
    int* gstart = (int*)alloc((size_t)(GG + 1) * 4);
    int* deg      = (int*)alloc((size_t)NN * 4);
    float* sbuck1 = (float*)alloc((size_t)NBUCK * 128 * 4);
    float* sbuck2 = (float*)alloc((size_t)NBUCK * 128 * 4);

    int ebk = (ETOT + 255) / 256;   // 1329
    int nodeblk = NN / 4;           // 5000 (NN % 4 == 0)

    // ---- pre: gbound | BcatT1 | BcatT2 | zero out/deg/sbuck (no memset dispatch) --
    pre1_kernel<<<510, 256, 0, stream>>>(bidx, gstart,
            W1, Wskip, W2, a_src1, a_dst1, a_src2, a_dst2, BT1, BT2,
            deg, sbuck1, sbuck2, out);

    // ---- layer 1 GEMM (1250 blocks) + degree-count+CSR-fill (1329) in one launch --
    gemm_mfma<6><<<1250 + ebk, 256, 0, stream>>>(x, BT1, NN, FIN,
            h4b, skip, esf, edf, 320, 1250, 1, ei, deg, csr);
    // ---- layer 1 aggregation (+bucketed BN stats) ----
    aggr_kernel<<<nodeblk, 256, 0, stream>>>(h4b, esf, edf, deg, csr, b1, gout,
            sbuck1);

    // ---- layer 2 GEMM with fused BN1+skip+GELU A-staging (writes hmid too) ----
    gemm_mfma_bn<5><<<1250, 256, 0, stream>>>(gout, skip, sbuck1, g1, be1, bskip,
            hmid, BT2, NN, CC, h4b, esf, edf, 256);
    aggr_kernel<<<nodeblk, 256, 0, stream>>>(h4b, esf, edf, deg, csr, b2, gout,
            sbuck2);
    bnapply2_kernel<<<NN * CC / 256, 256, 0, stream>>>(
        gout, sbuck2, g2, be2, hmid, bidx, gstart, out);
}